// Round 7
// baseline (686.915 us; speedup 1.0000x reference)
//
#include <hip/hip_runtime.h>

#define N_NODES 50000
#define N_EDGES 800000

typedef short  bf16x8 __attribute__((ext_vector_type(8)));
typedef float  f32x4  __attribute__((ext_vector_type(4)));

__device__ __forceinline__ unsigned short f2bf(float f) {
    unsigned u = __float_as_uint(f);
    u += 0x7FFF + ((u >> 16) & 1);          // RNE
    return (unsigned short)(u >> 16);
}

// Hard LDS fence: compiler barrier + drain of all outstanding DS ops.
// Needed at every cross-lane LDS write->read handoff: LDS data flow between
// lanes is invisible to single-thread alias analysis, so without this the
// compiler may hoist ds_reads above the ds_writes they depend on (R4-R6 bug).
#define LDS_FENCE() asm volatile("s_waitcnt lgkmcnt(0)" ::: "memory")

// ---------------------------------------------------------------------------
// Kernel 0: zero the output (harness poisons d_out with 0xAA)
// ---------------------------------------------------------------------------
__global__ void zero_out_kernel(float4* __restrict__ p, int n4) {
    int i = blockIdx.x * blockDim.x + threadIdx.x;
    if (i < n4) p[i] = make_float4(0.f, 0.f, 0.f, 0.f);
}

// ---------------------------------------------------------------------------
// Kernel 1: pack W2 (64x576 f32) into bf16 B-fragment order in d_ws.
// B-frag for (nt, ks): lane L holds B[k = ks*32 + (L>>4)*8 + j][n = nt*16 + (L&15)],
// j = 0..7 contiguous. Flat index: ((nt*2+ks)*64 + L)*8 + j.
// ---------------------------------------------------------------------------
__global__ void prep_kernel(const float* __restrict__ W2,
                            unsigned short* __restrict__ ws) {
    int gid = blockIdx.x * 256 + threadIdx.x;      // 36864 total
    if (gid >= 36864) return;
    int j    = gid & 7;
    int lane = (gid >> 3) & 63;
    int ks   = (gid >> 9) & 1;
    int nt   = gid >> 10;
    int k = ks * 32 + (lane >> 4) * 8 + j;
    int n = nt * 16 + (lane & 15);
    ws[gid] = f2bf(W2[k * 576 + n]);
}

// ---------------------------------------------------------------------------
// Kernel 2: fused conv. Block = 64 = ONE wave. Phase 1: fp32 scalar
// h = silu(emb@W1), h->LDS bf16. Phase 2: w = h@W2 via mfma 16x16x32,
// double-buffered XOR-swizzled w-tile roundtrip with hard LDS fences,
// fused scalar tensor-product consumption. Phase 3: LDS transpose ->
// lane-contiguous atomics.
// LDS (aliased, 11264 B): h [0,9216) -> w-bufs [0,5632)+[5632,11264)
//   -> out-tile [0,11264).
// ---------------------------------------------------------------------------
__global__ __launch_bounds__(64, 3) void conv_kernel(
    const float* __restrict__ pos,
    const float* __restrict__ f_in,
    const int*   __restrict__ esrc,
    const int*   __restrict__ edst,
    const float* __restrict__ W1,
    const unsigned short* __restrict__ ws,
    float*       __restrict__ f_out)
{
    __shared__ __align__(16) char smem[11264];
    float* shf = (float*)smem;
    const int lane  = threadIdx.x;
    const int e     = blockIdx.x * 64 + lane;
    const int wbase = blockIdx.x * 64;
    const int q   = lane >> 4;
    const int col = lane & 15;
    const int l3  = lane & 3;

    const bf16x8* wsBv = (const bf16x8*)ws;

    // --- early global prefetch: B-frags for chunks 0,1 ---------------------
    bf16x8 bq0[2], bq1[2];
    #pragma unroll
    for (int c = 0; c < 2; ++c) {
        bq0[c] = wsBv[c * 128 + lane];
        bq1[c] = wsBv[c * 128 + 64 + lane];
    }

    const int s = esrc[e];
    const int d = edst[e];

    // --- geometry -----------------------------------------------------------
    float px = pos[3*d+0] - pos[3*s+0];
    float py = pos[3*d+1] - pos[3*s+1];
    float pz = pos[3*d+2] - pos[3*s+2];
    float r  = sqrtf(px*px + py*py + pz*pz + 1e-12f);
    float inv_r = __builtin_amdgcn_rcpf(r);
    float ux = px*inv_r, uy = py*inv_r, uz = pz*inv_r;
    const float SQ3 = 1.7320508075688772f;
    float shx = SQ3*ux, shy = SQ3*uy, shz = SQ3*uz;

    // --- x = f_in[src] into VGPRs ------------------------------------------
    float x0[16], x1[24], dot[8];
    {
        const float4* xg4 = reinterpret_cast<const float4*>(f_in + (size_t)s * 40);
        float xr[40];
        #pragma unroll
        for (int q8 = 0; q8 < 10; ++q8) {
            float4 v = xg4[q8];
            xr[4*q8+0] = v.x; xr[4*q8+1] = v.y; xr[4*q8+2] = v.z; xr[4*q8+3] = v.w;
        }
        #pragma unroll
        for (int i = 0; i < 16; ++i) x0[i] = xr[i];
        #pragma unroll
        for (int i = 0; i < 24; ++i) x1[i] = xr[16+i];
        #pragma unroll
        for (int u = 0; u < 8; ++u)
            dot[u] = x1[3*u+0]*ux + x1[3*u+1]*uy + x1[3*u+2]*uz;  // = inv_s3*(x1.sh1)
    }

    // --- radial embedding (fp32) -------------------------------------------
    const float A = 1.14136f * 7.38905609893065f;   // 1.14136 * e^2
    const float inv_step = 17.0f / 5.0f;
    float emb[16];
    #pragma unroll
    for (int k = 0; k < 16; ++k) {
        float dd  = r * inv_step - (float)(k + 1);
        float d2v = dd * dd;
        float arg = -2.0f * __builtin_amdgcn_rcpf(1.0f - d2v);
        float val = A * __expf(arg);
        emb[k] = (d2v < 1.0f) ? val : 0.0f;
    }

    // === Phase 1: h = silu(emb @ W1) fp32 scalar, two halves of 32 =========
    // (W1 rows wave-uniform -> s_load; h stored bf16 to LDS rows stride 144B)
    #pragma unroll
    for (int half = 0; half < 2; ++half) {
        float h32[32];
        #pragma unroll
        for (int i = 0; i < 32; ++i) h32[i] = 0.f;
        #pragma unroll
        for (int k = 0; k < 16; ++k) {
            const float ek = emb[k];
            const float* w1row = W1 + k * 64 + half * 32;
            #pragma unroll
            for (int i = 0; i < 32; ++i) h32[i] = fmaf(ek, w1row[i], h32[i]);
        }
        unsigned hp[16];
        #pragma unroll
        for (int i = 0; i < 16; ++i) {
            float z0 = h32[2*i],   s0 = z0 * __builtin_amdgcn_rcpf(1.0f + __expf(-z0));
            float z1 = h32[2*i+1], s1 = z1 * __builtin_amdgcn_rcpf(1.0f + __expf(-z1));
            hp[i] = (unsigned)f2bf(s0) | ((unsigned)f2bf(s1) << 16);
        }
        uint4* hrow = (uint4*)(smem + lane * 144 + half * 64);
        hrow[0] = make_uint4(hp[0],  hp[1],  hp[2],  hp[3]);
        hrow[1] = make_uint4(hp[4],  hp[5],  hp[6],  hp[7]);
        hrow[2] = make_uint4(hp[8],  hp[9],  hp[10], hp[11]);
        hrow[3] = make_uint4(hp[12], hp[13], hp[14], hp[15]);
    }
    LDS_FENCE();                          // h stores visible before frag reads
    // h A-frags: edge m = mt*16+col, k = ks*32 + q*8 + j
    bf16x8 aF[4][2];
    #pragma unroll
    for (int mt = 0; mt < 4; ++mt)
        #pragma unroll
        for (int ks = 0; ks < 2; ++ks)
            aF[mt][ks] = *(const bf16x8*)(smem + (mt*16 + col)*144 + ks*64 + q*16);
    LDS_FENCE();                          // frag reads done before w-buf writes

    // === Phase 2: w = h @ W2 (MFMA) fused with tensor-product consumption ==
    float out0[16], t01[8], o1b[24];
    #pragma unroll
    for (int v = 0; v < 16; ++v) out0[v] = 0.f;
    #pragma unroll
    for (int v = 0; v < 8;  ++v) t01[v]  = 0.f;
    #pragma unroll
    for (int v = 0; v < 24; ++v) o1b[v]  = 0.f;

    // Store: edge q*4+rr, n-col=col -> row (q*4+rr)*20, col ((col>>2)^rr)*4+(col&3)
    // Read: edge=lane row, group kk at column group kk^(lane&3) -> wch[n]=w[n]
    int swc[4], roff[4];
    #pragma unroll
    for (int rr = 0; rr < 4; ++rr) {
        swc[rr]  = (((col >> 2) ^ rr) << 2) | (col & 3);
        roff[rr] = lane * 20 + ((rr ^ l3) << 2);
    }
    float wch[16];

#define GEMM_STORE(NT) { \
    f32x4 w0 = {0.f,0.f,0.f,0.f}, w1 = {0.f,0.f,0.f,0.f}; \
    f32x4 w2 = {0.f,0.f,0.f,0.f}, w3 = {0.f,0.f,0.f,0.f}; \
    w0 = __builtin_amdgcn_mfma_f32_16x16x32_bf16(aF[0][0], bq0[(NT)&1], w0, 0,0,0); \
    w1 = __builtin_amdgcn_mfma_f32_16x16x32_bf16(aF[1][0], bq0[(NT)&1], w1, 0,0,0); \
    w2 = __builtin_amdgcn_mfma_f32_16x16x32_bf16(aF[2][0], bq0[(NT)&1], w2, 0,0,0); \
    w3 = __builtin_amdgcn_mfma_f32_16x16x32_bf16(aF[3][0], bq0[(NT)&1], w3, 0,0,0); \
    w0 = __builtin_amdgcn_mfma_f32_16x16x32_bf16(aF[0][1], bq1[(NT)&1], w0, 0,0,0); \
    w1 = __builtin_amdgcn_mfma_f32_16x16x32_bf16(aF[1][1], bq1[(NT)&1], w1, 0,0,0); \
    w2 = __builtin_amdgcn_mfma_f32_16x16x32_bf16(aF[2][1], bq1[(NT)&1], w2, 0,0,0); \
    w3 = __builtin_amdgcn_mfma_f32_16x16x32_bf16(aF[3][1], bq1[(NT)&1], w3, 0,0,0); \
    if ((NT) + 2 < 36) { \
        bq0[(NT)&1] = wsBv[((NT)+2)*128 + lane]; \
        bq1[(NT)&1] = wsBv[((NT)+2)*128 + 64 + lane]; \
    } \
    float* bb = shf + ((NT)&1)*1408; \
    bb[  0 + q*80 +  0 + swc[0]] = w0[0]; \
    bb[  0 + q*80 + 20 + swc[1]] = w0[1]; \
    bb[  0 + q*80 + 40 + swc[2]] = w0[2]; \
    bb[  0 + q*80 + 60 + swc[3]] = w0[3]; \
    bb[320 + q*80 +  0 + swc[0]] = w1[0]; \
    bb[320 + q*80 + 20 + swc[1]] = w1[1]; \
    bb[320 + q*80 + 40 + swc[2]] = w1[2]; \
    bb[320 + q*80 + 60 + swc[3]] = w1[3]; \
    bb[640 + q*80 +  0 + swc[0]] = w2[0]; \
    bb[640 + q*80 + 20 + swc[1]] = w2[1]; \
    bb[640 + q*80 + 40 + swc[2]] = w2[2]; \
    bb[640 + q*80 + 60 + swc[3]] = w2[3]; \
    bb[960 + q*80 +  0 + swc[0]] = w3[0]; \
    bb[960 + q*80 + 20 + swc[1]] = w3[1]; \
    bb[960 + q*80 + 40 + swc[2]] = w3[2]; \
    bb[960 + q*80 + 60 + swc[3]] = w3[3]; \
    }

#define LOADW(PT) { \
    LDS_FENCE();  /* all lanes' chunk-(PT) stores visible before reads */ \
    const float* bb = shf + ((PT)&1)*1408; \
    f32x4 rg0 = *(const f32x4*)(bb + roff[0]); \
    f32x4 rg1 = *(const f32x4*)(bb + roff[1]); \
    f32x4 rg2 = *(const f32x4*)(bb + roff[2]); \
    f32x4 rg3 = *(const f32x4*)(bb + roff[3]); \
    wch[0]=rg0[0]; wch[1]=rg0[1]; wch[2]=rg0[2]; wch[3]=rg0[3]; \
    wch[4]=rg1[0]; wch[5]=rg1[1]; wch[6]=rg1[2]; wch[7]=rg1[3]; \
    wch[8]=rg2[0]; wch[9]=rg2[1]; wch[10]=rg2[2]; wch[11]=rg2[3]; \
    wch[12]=rg3[0]; wch[13]=rg3[1]; wch[14]=rg3[2]; wch[15]=rg3[3]; \
    }

    GEMM_STORE(0);
    #pragma unroll
    for (int cc = 1; cc <= 36; ++cc) {
        const int P = cc - 1;
        LOADW(P);
        if (cc < 36) GEMM_STORE(cc);
        // consume chunk P (path selection constant-folds under full unroll)
        if (P < 16) {                       // w00: out0[v] += w00[u=P][v]*x0[P]
            const float xv = x0[P];
            #pragma unroll
            for (int v = 0; v < 16; ++v) out0[v] = fmaf(wch[v], xv, out0[v]);
        } else if (P < 24) {                // w01: t01[v] += w01[u][v]*x0[u]
            const int t = P - 16;
            const float xa = x0[2*t], xb = x0[2*t+1];
            #pragma unroll
            for (int v = 0; v < 8; ++v)
                t01[v] = fmaf(wch[v], xa, fmaf(wch[8+v], xb, t01[v]));
        } else if (P < 28) {                // w10: o1b[v][k] += w10[u][v]*x1[u][k]
            const int u0 = (P - 24) * 2;
            const float xa0 = x1[3*u0+0], xa1 = x1[3*u0+1], xa2 = x1[3*u0+2];
            const float xb0 = x1[3*u0+3], xb1 = x1[3*u0+4], xb2 = x1[3*u0+5];
            #pragma unroll
            for (int v = 0; v < 8; ++v) {
                o1b[3*v+0] = fmaf(wch[v], xa0, fmaf(wch[8+v], xb0, o1b[3*v+0]));
                o1b[3*v+1] = fmaf(wch[v], xa1, fmaf(wch[8+v], xb1, o1b[3*v+1]));
                o1b[3*v+2] = fmaf(wch[v], xa2, fmaf(wch[8+v], xb2, o1b[3*v+2]));
            }
        } else {                            // w11: out0[v] += w11[u][v]*dot[u]
            const float dv = dot[P - 28];
            #pragma unroll
            for (int v = 0; v < 16; ++v) out0[v] = fmaf(wch[v], dv, out0[v]);
        }
    }
#undef GEMM_STORE
#undef LOADW

    // === Phase 3: scale, transpose through LDS, lane-contiguous atomics ====
    const float S = 1.0f / (32.0f * 4.898979485566356f);
    float fo[40];
    #pragma unroll
    for (int v = 0; v < 16; ++v) fo[v] = S * out0[v];
    #pragma unroll
    for (int v = 0; v < 8; ++v) {
        fo[16+3*v+0] = S * fmaf(t01[v], shx, o1b[3*v+0]);
        fo[16+3*v+1] = S * fmaf(t01[v], shy, o1b[3*v+1]);
        fo[16+3*v+2] = S * fmaf(t01[v], shz, o1b[3*v+2]);
    }
    LDS_FENCE();                          // last w-buf reads done before overwrite
    {   // out-tile: stride 44 floats per edge
        float4* orow = (float4*)(shf + lane * 44);
        #pragma unroll
        for (int g = 0; g < 10; ++g)
            orow[g] = make_float4(fo[4*g], fo[4*g+1], fo[4*g+2], fo[4*g+3]);
    }
    LDS_FENCE();                          // out-tile stores visible before gather
    #pragma unroll 4
    for (int it = 0; it < 40; ++it) {
        int p  = it * 64 + lane;
        int ee = (p * 52429) >> 21;      // p / 40, exact for p < 4096
        int c  = p - ee * 40;
        float v = shf[ee * 44 + c];
        int dd = edst[wbase + ee];
        atomicAdd(f_out + (size_t)dd * 40 + c, v);
    }
}

extern "C" void kernel_launch(void* const* d_in, const int* in_sizes, int n_in,
                              void* d_out, int out_size, void* d_ws, size_t ws_size,
                              hipStream_t stream) {
    const float* pos  = (const float*)d_in[0];
    const float* f_in = (const float*)d_in[1];
    const int*   esrc = (const int*)  d_in[2];
    const int*   edst = (const int*)  d_in[3];
    const float* W1   = (const float*)d_in[4];
    const float* W2   = (const float*)d_in[5];
    float* out = (float*)d_out;
    unsigned short* ws = (unsigned short*)d_ws;   // 36864 bf16 = 72 KiB

    const int n4 = (N_NODES * 40) / 4;
    zero_out_kernel<<<(n4 + 255) / 256, 256, 0, stream>>>((float4*)out, n4);
    prep_kernel<<<144, 256, 0, stream>>>(W2, ws);

    conv_kernel<<<N_EDGES / 64, 64, 0, stream>>>(pos, f_in, esrc, edst, W1, ws, out);
}